// Round 1
// baseline (34533.023 us; speedup 1.0000x reference)
//
#include <hip/hip_runtime.h>

#define SLEN  128
#define TLEN  64
#define BATCH 64
#define EMB   512
#define HID   512
#define DDEC  1024
#define ATT   256
#define VOC   32000
#define TSTEPS 63   // T-1 decode steps

// ---------- helpers ----------
__device__ __forceinline__ float sigmoidf_(float x) { return 1.0f / (1.0f + __expf(-x)); }
__device__ __forceinline__ float tanhf_(float x)    { return 1.0f - 2.0f / (__expf(2.0f * x) + 1.0f); }
__device__ __forceinline__ float dot4(float4 a, float4 b) {
    return a.x * b.x + a.y * b.y + a.z * b.z + a.w * b.w;
}

// ---------- K0: init (zero enc h/c parity-0, zero out row 0, gather dec emb into pred_in) ----------
// sizes: 131072 (hc par0) + 2048000 (out row0) + 2064384 (63*64*512 gather)
__global__ __launch_bounds__(256) void init_all(
    const int* __restrict__ trg, const float* __restrict__ dec_emb,
    float* __restrict__ hc_enc, float* __restrict__ out_row0, float* __restrict__ pred_in)
{
    long idx = (long)blockIdx.x * 256 + threadIdx.x;
    if (idx < 131072) { hc_enc[idx] = 0.0f; return; }
    idx -= 131072;
    if (idx < 2048000) { out_row0[idx] = 0.0f; return; }
    idx -= 2048000;
    if (idx < (long)TSTEPS * BATCH * EMB) {
        int r = (int)(idx / EMB), e = (int)(idx % EMB);
        int t = r >> 6, b = r & 63;
        int tok = trg[t * BATCH + b];
        pred_in[(long)r * 2560 + 2048 + e] = dec_emb[(long)tok * EMB + e];
    }
}

// ---------- encoder step (both directions in one launch) ----------
// grid 256 blocks x 256 thr: bx>>7 = dir, (bx&127)*4 + (tid>>6) = d, tid&63 = b
// hc_enc layout: [par][4][B*H] with order h_f, c_f, h_b, c_b  (each 32768 floats)
__global__ __launch_bounds__(256) void enc_step(
    const int* __restrict__ src, const float* __restrict__ emb,
    const float* __restrict__ Wf_ih, const float* __restrict__ Wf_hh, const float* __restrict__ bf,
    const float* __restrict__ Wb_ih, const float* __restrict__ Wb_hh, const float* __restrict__ bb,
    float* __restrict__ hc, float* __restrict__ enc_out, int s)
{
    const int tid = threadIdx.x;
    const int b = tid & 63, dl = tid >> 6;
    const int bx = blockIdx.x;
    const int dir = bx >> 7;
    const int d = (bx & 127) * 4 + dl;
    const int par = s & 1;
    const int s_eff = dir ? (SLEN - 1 - s) : s;

    const float* Wih = dir ? Wb_ih : Wf_ih;
    const float* Whh = dir ? Wb_hh : Wf_hh;
    const float* bias = dir ? bb : bf;

    float* hcur = hc + par * 131072 + dir * 65536;
    float* ccur = hcur + 32768;
    float* hnxt = hc + (par ^ 1) * 131072 + dir * 65536;
    float* cnxt = hnxt + 32768;

    const int tok = src[s_eff * BATCH + b];
    const float4* xi = (const float4*)(emb + (long)tok * EMB);
    const float4* hi = (const float4*)(hcur + b * HID);
    const float4* wi0 = (const float4*)(Wih + (long)(0 * HID + d) * EMB);
    const float4* wi1 = (const float4*)(Wih + (long)(1 * HID + d) * EMB);
    const float4* wi2 = (const float4*)(Wih + (long)(2 * HID + d) * EMB);
    const float4* wi3 = (const float4*)(Wih + (long)(3 * HID + d) * EMB);
    const float4* wh0 = (const float4*)(Whh + (long)(0 * HID + d) * HID);
    const float4* wh1 = (const float4*)(Whh + (long)(1 * HID + d) * HID);
    const float4* wh2 = (const float4*)(Whh + (long)(2 * HID + d) * HID);
    const float4* wh3 = (const float4*)(Whh + (long)(3 * HID + d) * HID);

    float g0 = 0.f, g1 = 0.f, g2 = 0.f, g3 = 0.f;
    #pragma unroll 8
    for (int k = 0; k < EMB / 4; ++k) {
        float4 x = xi[k];
        g0 += dot4(x, wi0[k]); g1 += dot4(x, wi1[k]);
        g2 += dot4(x, wi2[k]); g3 += dot4(x, wi3[k]);
    }
    #pragma unroll 8
    for (int k = 0; k < HID / 4; ++k) {
        float4 hv = hi[k];
        g0 += dot4(hv, wh0[k]); g1 += dot4(hv, wh1[k]);
        g2 += dot4(hv, wh2[k]); g3 += dot4(hv, wh3[k]);
    }
    g0 += bias[d]; g1 += bias[HID + d]; g2 += bias[2 * HID + d]; g3 += bias[3 * HID + d];

    const float co = ccur[b * HID + d];
    const float c2 = sigmoidf_(g1) * co + sigmoidf_(g0) * tanhf_(g2);
    const float h2 = sigmoidf_(g3) * tanhf_(c2);
    hnxt[b * HID + d] = h2;
    cnxt[b * HID + d] = c2;
    enc_out[((long)s_eff * BATCH + b) * (2 * HID) + dir * HID + d] = h2;
}

// ---------- decoder init: h0 = [hf|hb], c0 = [cf|cb] into parity-0 buffers ----------
__global__ __launch_bounds__(256) void dec_init(
    const float* __restrict__ hc_enc, float* __restrict__ hdec0, float* __restrict__ cdec0)
{
    int idx = blockIdx.x * 256 + threadIdx.x;   // 0..131071
    int which = idx >> 16;                      // 0: h, 1: c
    int r = idx & 65535;
    int b = r >> 10, d = r & 1023;
    const float* hf = hc_enc + 0;
    const float* cf = hc_enc + 32768;
    const float* hb = hc_enc + 65536;
    const float* cb = hc_enc + 98304;
    float val;
    if (which == 0) val = (d < HID) ? hf[b * HID + d] : hb[b * HID + d - HID];
    else            val = (d < HID) ? cf[b * HID + d] : cb[b * HID + d - HID];
    (which ? cdec0 : hdec0)[b * DDEC + d] = val;
}

// ---------- h_att = h @ Wa[:, :D]^T  ([B,1024] -> [B,256]) ----------
// grid (16,4): block handles 16 j x 16 b
__global__ __launch_bounds__(256) void hatt_step(
    const float* __restrict__ hdec, const float* __restrict__ Wa, float* __restrict__ hatt)
{
    const int jl = threadIdx.x & 15, bl = threadIdx.x >> 4;
    const int j = blockIdx.x * 16 + jl;
    const int b = blockIdx.y * 16 + bl;
    const float4* w4 = (const float4*)(Wa + (long)j * 2048);       // first 1024 cols
    const float4* h4 = (const float4*)(hdec + (long)b * DDEC);
    float acc = 0.f;
    #pragma unroll 8
    for (int k = 0; k < DDEC / 4; ++k) acc += dot4(w4[k], h4[k]);
    hatt[b * ATT + j] = acc;
}

// ---------- attention: scores -> softmax -> ctx (writes ctx into pred_in) ----------
// grid BATCH blocks x 256 thr
__global__ __launch_bounds__(256) void attn_step(
    const int* __restrict__ src, const float* __restrict__ hatt, const float* __restrict__ vvec,
    const float* __restrict__ enc_part, const float* __restrict__ enc_out,
    float* __restrict__ pred_in, int t)
{
    __shared__ float ha[ATT];
    __shared__ float sv[ATT];
    __shared__ float sc[SLEN];
    __shared__ float red[SLEN];
    const int b = blockIdx.x, tid = threadIdx.x;
    ha[tid] = hatt[b * ATT + tid];
    sv[tid] = vvec[tid];
    __syncthreads();

    if (tid < SLEN) {
        const float* ep = enc_part + ((long)tid * BATCH + b) * ATT;
        float acc = 0.f;
        #pragma unroll 4
        for (int j = 0; j < ATT; ++j) acc += tanhf_(ha[j] + ep[j]) * sv[j];
        sc[tid] = (src[tid * BATCH + b] != 0) ? acc : -1e10f;
        red[tid] = sc[tid];
    }
    __syncthreads();
    for (int off = 64; off > 0; off >>= 1) {
        if (tid < off) red[tid] = fmaxf(red[tid], red[tid + off]);
        __syncthreads();
    }
    const float mx = red[0];
    __syncthreads();
    if (tid < SLEN) {
        float e = __expf(sc[tid] - mx);
        sc[tid] = e;
        red[tid] = e;
    }
    __syncthreads();
    for (int off = 64; off > 0; off >>= 1) {
        if (tid < off) red[tid] += red[tid + off];
        __syncthreads();
    }
    const float inv = 1.0f / red[0];
    __syncthreads();

    // ctx: each thread owns 4 consecutive e dims (tid*4..+3)
    float a0 = 0.f, a1 = 0.f, a2 = 0.f, a3 = 0.f;
    for (int sI = 0; sI < SLEN; ++sI) {
        const float as = sc[sI] * inv;
        const float4 ev = ((const float4*)(enc_out + ((long)sI * BATCH + b) * (2 * HID)))[tid];
        a0 += as * ev.x; a1 += as * ev.y; a2 += as * ev.z; a3 += as * ev.w;
    }
    float4 o; o.x = a0; o.y = a1; o.z = a2; o.w = a3;
    *(float4*)(pred_in + ((long)t * BATCH + b) * 2560 + 1024 + tid * 4) = o;
}

// ---------- decoder LSTM step: gates + pointwise, h2 -> pred_in ----------
// grid 256 blocks x 256 thr: d = bx*4 + tid>>6, b = tid&63
__global__ __launch_bounds__(256) void dec_step(
    const float* __restrict__ Wd_ih, const float* __restrict__ Wd_hh, const float* __restrict__ bd,
    const float* __restrict__ hcur, const float* __restrict__ ccur,
    float* __restrict__ hnxt, float* __restrict__ cnxt,
    float* __restrict__ pred_in, int t)
{
    const int tid = threadIdx.x;
    const int b = tid & 63, dl = tid >> 6;
    const int d = blockIdx.x * 4 + dl;

    const float* prow = pred_in + ((long)t * BATCH + b) * 2560;
    const float4* xe = (const float4*)(prow + 2048);   // emb_t  (512)
    const float4* xc = (const float4*)(prow + 1024);   // ctx    (1024)
    const float4* h4 = (const float4*)(hcur + (long)b * DDEC);

    const float4* wi[4]; const float4* wh[4];
    #pragma unroll
    for (int q = 0; q < 4; ++q) {
        wi[q] = (const float4*)(Wd_ih + (long)(q * DDEC + d) * 1536);
        wh[q] = (const float4*)(Wd_hh + (long)(q * DDEC + d) * DDEC);
    }
    float g[4] = {0.f, 0.f, 0.f, 0.f};
    #pragma unroll 4
    for (int k = 0; k < EMB / 4; ++k) {          // x[0:512] = emb, W cols 0..511
        float4 x = xe[k];
        #pragma unroll
        for (int q = 0; q < 4; ++q) g[q] += dot4(x, wi[q][k]);
    }
    #pragma unroll 4
    for (int k = 0; k < 256; ++k) {              // x[512:1536] = ctx, W cols 512..1535
        float4 x = xc[k];
        #pragma unroll
        for (int q = 0; q < 4; ++q) g[q] += dot4(x, wi[q][128 + k]);
    }
    #pragma unroll 4
    for (int k = 0; k < DDEC / 4; ++k) {         // h part
        float4 hv = h4[k];
        #pragma unroll
        for (int q = 0; q < 4; ++q) g[q] += dot4(hv, wh[q][k]);
    }
    #pragma unroll
    for (int q = 0; q < 4; ++q) g[q] += bd[q * DDEC + d];

    const float co = ccur[(long)b * DDEC + d];
    const float c2 = sigmoidf_(g[1]) * co + sigmoidf_(g[0]) * tanhf_(g[2]);
    const float h2 = sigmoidf_(g[3]) * tanhf_(c2);
    hnxt[(long)b * DDEC + d] = h2;
    cnxt[(long)b * DDEC + d] = c2;
    pred_in[((long)t * BATCH + b) * 2560 + d] = h2;
}

// ---------- generic fp32 GEMM: C[M,N] = A[M,K] @ B[N,K]^T + bias ----------
// tile 64x64, K-chunk 16; grid (N/64, M/64), 256 thr
__global__ __launch_bounds__(256) void gemm_abt(
    const float* __restrict__ A, int lda,
    const float* __restrict__ Bm, int ldb,
    const float* __restrict__ bias,
    float* __restrict__ C, int ldc, int K)
{
    __shared__ float As[16][68];
    __shared__ float Bs[16][68];
    const int tid = threadIdx.x;
    const int tx = tid & 15, ty = tid >> 4;
    const int lr = tid >> 2;            // 0..63
    const int lk = (tid & 3) << 2;      // 0,4,8,12
    const long m0 = (long)blockIdx.y << 6;
    const long n0 = (long)blockIdx.x << 6;
    const float* Ap = A + (m0 + lr) * lda + lk;
    const float* Bp = Bm + (n0 + lr) * ldb + lk;
    float acc[4][4] = {};

    for (int kc = 0; kc < K; kc += 16) {
        float4 av = *(const float4*)(Ap + kc);
        float4 bv = *(const float4*)(Bp + kc);
        As[lk + 0][lr] = av.x; As[lk + 1][lr] = av.y; As[lk + 2][lr] = av.z; As[lk + 3][lr] = av.w;
        Bs[lk + 0][lr] = bv.x; Bs[lk + 1][lr] = bv.y; Bs[lk + 2][lr] = bv.z; Bs[lk + 3][lr] = bv.w;
        __syncthreads();
        #pragma unroll
        for (int kk = 0; kk < 16; ++kk) {
            float4 a = *(const float4*)&As[kk][ty << 2];
            float4 b = *(const float4*)&Bs[kk][tx << 2];
            const float aa[4] = {a.x, a.y, a.z, a.w};
            const float bb2[4] = {b.x, b.y, b.z, b.w};
            #pragma unroll
            for (int i2 = 0; i2 < 4; ++i2)
                #pragma unroll
                for (int j2 = 0; j2 < 4; ++j2)
                    acc[i2][j2] += aa[i2] * bb2[j2];
        }
        __syncthreads();
    }
    float4 bvv = {0.f, 0.f, 0.f, 0.f};
    if (bias) bvv = *(const float4*)(bias + n0 + (tx << 2));
    #pragma unroll
    for (int i2 = 0; i2 < 4; ++i2) {
        float4 o;
        o.x = acc[i2][0] + bvv.x; o.y = acc[i2][1] + bvv.y;
        o.z = acc[i2][2] + bvv.z; o.w = acc[i2][3] + bvv.w;
        *(float4*)(C + (m0 + (ty << 2) + i2) * ldc + n0 + (tx << 2)) = o;
    }
}

// ---------- launch ----------
extern "C" void kernel_launch(void* const* d_in, const int* in_sizes, int n_in,
                              void* d_out, int out_size, void* d_ws, size_t ws_size,
                              hipStream_t stream) {
    const int*   src     = (const int*)d_in[0];
    const int*   trg     = (const int*)d_in[1];
    const float* enc_emb = (const float*)d_in[2];
    const float* Wf_ih   = (const float*)d_in[3];
    const float* Wf_hh   = (const float*)d_in[4];
    const float* bf      = (const float*)d_in[5];
    const float* Wb_ih   = (const float*)d_in[6];
    const float* Wb_hh   = (const float*)d_in[7];
    const float* bb      = (const float*)d_in[8];
    const float* Wa      = (const float*)d_in[9];
    const float* ba      = (const float*)d_in[10];
    const float* vvec    = (const float*)d_in[11];
    const float* dec_emb = (const float*)d_in[12];
    const float* Wd_ih   = (const float*)d_in[13];
    const float* Wd_hh   = (const float*)d_in[14];
    const float* bd      = (const float*)d_in[15];
    const float* Wo      = (const float*)d_in[16];
    const float* bo      = (const float*)d_in[17];
    float* out = (float*)d_out;

    // workspace layout (floats)
    float* ws_f     = (float*)d_ws;
    float* enc_out  = ws_f;                       // 8388608  [S,B,2H]
    float* enc_part = enc_out + 8388608;          // 2097152  [S,B,A]
    float* hc_enc   = enc_part + 2097152;         // 262144   [2][4][B*H]
    float* h_dec    = hc_enc + 262144;            // 131072   [2][B*D]
    float* c_dec    = h_dec + 131072;             // 131072
    float* h_att    = c_dec + 131072;             // 16384    [B,A]
    float* pred_in  = h_att + 16384;              // 10321920 [4032, 2560] = [h2|ctx|emb]
    const size_t need_bytes = (size_t)(10321920 + 16384 + 131072 + 131072 + 262144 + 2097152 + 8388608) * 4;
    if (ws_size < need_bytes) return;             // cannot run safely

    // K0: init (zero hc par0, zero out row0, gather dec embeddings into pred_in)
    {
        long n = 131072L + 2048000L + (long)TSTEPS * BATCH * EMB;
        int blocks = (int)((n + 255) / 256);
        init_all<<<blocks, 256, 0, stream>>>(trg, dec_emb, hc_enc, out, pred_in);
    }
    // encoder: 128 sequential steps (fwd+bwd per launch)
    for (int s = 0; s < SLEN; ++s)
        enc_step<<<256, 256, 0, stream>>>(src, enc_emb, Wf_ih, Wf_hh, bf, Wb_ih, Wb_hh, bb,
                                          hc_enc, enc_out, s);
    // enc_part = enc_out @ Wa[:,1024:2048]^T + ba   (M=8192,N=256,K=1024)
    gemm_abt<<<dim3(ATT / 64, (SLEN * BATCH) / 64), 256, 0, stream>>>(
        enc_out, 2 * HID, Wa + 1024, 2048, ba, enc_part, ATT, 1024);
    // decoder init
    dec_init<<<512, 256, 0, stream>>>(hc_enc, h_dec, c_dec);

    for (int t = 0; t < TSTEPS; ++t) {
        const int par = t & 1;
        const float* hcur = h_dec + par * 65536;
        const float* ccur = c_dec + par * 65536;
        float* hnxt = h_dec + (par ^ 1) * 65536;
        float* cnxt = c_dec + (par ^ 1) * 65536;
        hatt_step<<<dim3(16, 4), 256, 0, stream>>>(hcur, Wa, h_att);
        attn_step<<<BATCH, 256, 0, stream>>>(src, h_att, vvec, enc_part, enc_out, pred_in, t);
        dec_step<<<256, 256, 0, stream>>>(Wd_ih, Wd_hh, bd, hcur, ccur, hnxt, cnxt, pred_in, t);
    }
    // final projection: [4032,2560] @ Wo[32000,2560]^T + bo -> out rows 64..4095
    gemm_abt<<<dim3(VOC / 64, (TSTEPS * BATCH) / 64), 256, 0, stream>>>(
        pred_in, 2560, Wo, 2560, bo, out + (long)BATCH * VOC, VOC, 2560);
}

// Round 2
// 25652.457 us; speedup vs baseline: 1.3462x; 1.3462x over previous
//
#include <hip/hip_runtime.h>

#define SLEN  128
#define TLEN  64
#define BATCH 64
#define EMB   512
#define HID   512
#define DDEC  1024
#define ATT   256
#define VOC   32000
#define TSTEPS 63   // T-1 decode steps

typedef _Float16 f16x4 __attribute__((ext_vector_type(4)));
typedef _Float16 f16x8 __attribute__((ext_vector_type(8)));
typedef float    f32x4 __attribute__((ext_vector_type(4)));

// ---------- helpers ----------
__device__ __forceinline__ float sigmoidf_(float x) { return 1.0f / (1.0f + __expf(-x)); }
__device__ __forceinline__ float tanhf_(float x)    { return 1.0f - 2.0f / (__expf(2.0f * x) + 1.0f); }
__device__ __forceinline__ float dot4(float4 a, float4 b) {
    return a.x * b.x + a.y * b.y + a.z * b.z + a.w * b.w;
}

// ---------- K0: init ----------
__global__ __launch_bounds__(256) void init_all(
    const int* __restrict__ trg, const float* __restrict__ dec_emb,
    float* __restrict__ hc_enc, float* __restrict__ out_row0, float* __restrict__ pred_in)
{
    long idx = (long)blockIdx.x * 256 + threadIdx.x;
    if (idx < 131072) { hc_enc[idx] = 0.0f; return; }
    idx -= 131072;
    if (idx < 2048000) { out_row0[idx] = 0.0f; return; }
    idx -= 2048000;
    if (idx < (long)TSTEPS * BATCH * EMB) {
        int r = (int)(idx / EMB), e = (int)(idx % EMB);
        int t = r >> 6, b = r & 63;
        int tok = trg[t * BATCH + b];
        pred_in[(long)r * 2560 + 2048 + e] = dec_emb[(long)tok * EMB + e];
    }
}

// ---------- encoder step (both directions in one launch) ----------
__global__ __launch_bounds__(256) void enc_step(
    const int* __restrict__ src, const float* __restrict__ emb,
    const float* __restrict__ Wf_ih, const float* __restrict__ Wf_hh, const float* __restrict__ bf,
    const float* __restrict__ Wb_ih, const float* __restrict__ Wb_hh, const float* __restrict__ bb,
    float* __restrict__ hc, float* __restrict__ enc_out, int s)
{
    const int tid = threadIdx.x;
    const int b = tid & 63, dl = tid >> 6;
    const int bx = blockIdx.x;
    const int dir = bx >> 7;
    const int d = (bx & 127) * 4 + dl;
    const int par = s & 1;
    const int s_eff = dir ? (SLEN - 1 - s) : s;

    const float* Wih = dir ? Wb_ih : Wf_ih;
    const float* Whh = dir ? Wb_hh : Wf_hh;
    const float* bias = dir ? bb : bf;

    float* hcur = hc + par * 131072 + dir * 65536;
    float* ccur = hcur + 32768;
    float* hnxt = hc + (par ^ 1) * 131072 + dir * 65536;
    float* cnxt = hnxt + 32768;

    const int tok = src[s_eff * BATCH + b];
    const float4* xi = (const float4*)(emb + (long)tok * EMB);
    const float4* hi = (const float4*)(hcur + b * HID);
    const float4* wi0 = (const float4*)(Wih + (long)(0 * HID + d) * EMB);
    const float4* wi1 = (const float4*)(Wih + (long)(1 * HID + d) * EMB);
    const float4* wi2 = (const float4*)(Wih + (long)(2 * HID + d) * EMB);
    const float4* wi3 = (const float4*)(Wih + (long)(3 * HID + d) * EMB);
    const float4* wh0 = (const float4*)(Whh + (long)(0 * HID + d) * HID);
    const float4* wh1 = (const float4*)(Whh + (long)(1 * HID + d) * HID);
    const float4* wh2 = (const float4*)(Whh + (long)(2 * HID + d) * HID);
    const float4* wh3 = (const float4*)(Whh + (long)(3 * HID + d) * HID);

    float g0 = 0.f, g1 = 0.f, g2 = 0.f, g3 = 0.f;
    #pragma unroll 8
    for (int k = 0; k < EMB / 4; ++k) {
        float4 x = xi[k];
        g0 += dot4(x, wi0[k]); g1 += dot4(x, wi1[k]);
        g2 += dot4(x, wi2[k]); g3 += dot4(x, wi3[k]);
    }
    #pragma unroll 8
    for (int k = 0; k < HID / 4; ++k) {
        float4 hv = hi[k];
        g0 += dot4(hv, wh0[k]); g1 += dot4(hv, wh1[k]);
        g2 += dot4(hv, wh2[k]); g3 += dot4(hv, wh3[k]);
    }
    g0 += bias[d]; g1 += bias[HID + d]; g2 += bias[2 * HID + d]; g3 += bias[3 * HID + d];

    const float co = ccur[b * HID + d];
    const float c2 = sigmoidf_(g1) * co + sigmoidf_(g0) * tanhf_(g2);
    const float h2 = sigmoidf_(g3) * tanhf_(c2);
    hnxt[b * HID + d] = h2;
    cnxt[b * HID + d] = c2;
    enc_out[((long)s_eff * BATCH + b) * (2 * HID) + dir * HID + d] = h2;
}

// ---------- decoder init ----------
__global__ __launch_bounds__(256) void dec_init(
    const float* __restrict__ hc_enc, float* __restrict__ hdec0, float* __restrict__ cdec0)
{
    int idx = blockIdx.x * 256 + threadIdx.x;   // 0..131071
    int which = idx >> 16;
    int r = idx & 65535;
    int b = r >> 10, d = r & 1023;
    const float* hf = hc_enc + 0;
    const float* cf = hc_enc + 32768;
    const float* hb = hc_enc + 65536;
    const float* cb = hc_enc + 98304;
    float val;
    if (which == 0) val = (d < HID) ? hf[b * HID + d] : hb[b * HID + d - HID];
    else            val = (d < HID) ? cf[b * HID + d] : cb[b * HID + d - HID];
    (which ? cdec0 : hdec0)[b * DDEC + d] = val;
}

// ---------- h_att = h @ Wa[:, :D]^T ----------
__global__ __launch_bounds__(256) void hatt_step(
    const float* __restrict__ hdec, const float* __restrict__ Wa, float* __restrict__ hatt)
{
    const int jl = threadIdx.x & 15, bl = threadIdx.x >> 4;
    const int j = blockIdx.x * 16 + jl;
    const int b = blockIdx.y * 16 + bl;
    const float4* w4 = (const float4*)(Wa + (long)j * 2048);
    const float4* h4 = (const float4*)(hdec + (long)b * DDEC);
    float acc = 0.f;
    #pragma unroll 8
    for (int k = 0; k < DDEC / 4; ++k) acc += dot4(w4[k], h4[k]);
    hatt[b * ATT + j] = acc;
}

// ---------- attention ----------
__global__ __launch_bounds__(256) void attn_step(
    const int* __restrict__ src, const float* __restrict__ hatt, const float* __restrict__ vvec,
    const float* __restrict__ enc_part, const float* __restrict__ enc_out,
    float* __restrict__ pred_in, int t)
{
    __shared__ float ha[ATT];
    __shared__ float sv[ATT];
    __shared__ float sc[SLEN];
    __shared__ float red[SLEN];
    const int b = blockIdx.x, tid = threadIdx.x;
    ha[tid] = hatt[b * ATT + tid];
    sv[tid] = vvec[tid];
    __syncthreads();

    if (tid < SLEN) {
        const float* ep = enc_part + ((long)tid * BATCH + b) * ATT;
        float acc = 0.f;
        #pragma unroll 4
        for (int j = 0; j < ATT; ++j) acc += tanhf_(ha[j] + ep[j]) * sv[j];
        sc[tid] = (src[tid * BATCH + b] != 0) ? acc : -1e10f;
        red[tid] = sc[tid];
    }
    __syncthreads();
    for (int off = 64; off > 0; off >>= 1) {
        if (tid < off) red[tid] = fmaxf(red[tid], red[tid + off]);
        __syncthreads();
    }
    const float mx = red[0];
    __syncthreads();
    if (tid < SLEN) {
        float e = __expf(sc[tid] - mx);
        sc[tid] = e;
        red[tid] = e;
    }
    __syncthreads();
    for (int off = 64; off > 0; off >>= 1) {
        if (tid < off) red[tid] += red[tid + off];
        __syncthreads();
    }
    const float inv = 1.0f / red[0];
    __syncthreads();

    float a0 = 0.f, a1 = 0.f, a2 = 0.f, a3 = 0.f;
    for (int sI = 0; sI < SLEN; ++sI) {
        const float as = sc[sI] * inv;
        const float4 ev = ((const float4*)(enc_out + ((long)sI * BATCH + b) * (2 * HID)))[tid];
        a0 += as * ev.x; a1 += as * ev.y; a2 += as * ev.z; a3 += as * ev.w;
    }
    float4 o; o.x = a0; o.y = a1; o.z = a2; o.w = a3;
    *(float4*)(pred_in + ((long)t * BATCH + b) * 2560 + 1024 + tid * 4) = o;
}

// ---------- decoder LSTM step ----------
__global__ __launch_bounds__(256) void dec_step(
    const float* __restrict__ Wd_ih, const float* __restrict__ Wd_hh, const float* __restrict__ bd,
    const float* __restrict__ hcur, const float* __restrict__ ccur,
    float* __restrict__ hnxt, float* __restrict__ cnxt,
    float* __restrict__ pred_in, int t)
{
    const int tid = threadIdx.x;
    const int b = tid & 63, dl = tid >> 6;
    const int d = blockIdx.x * 4 + dl;

    const float* prow = pred_in + ((long)t * BATCH + b) * 2560;
    const float4* xe = (const float4*)(prow + 2048);
    const float4* xc = (const float4*)(prow + 1024);
    const float4* h4 = (const float4*)(hcur + (long)b * DDEC);

    const float4* wi[4]; const float4* wh[4];
    #pragma unroll
    for (int q = 0; q < 4; ++q) {
        wi[q] = (const float4*)(Wd_ih + (long)(q * DDEC + d) * 1536);
        wh[q] = (const float4*)(Wd_hh + (long)(q * DDEC + d) * DDEC);
    }
    float g[4] = {0.f, 0.f, 0.f, 0.f};
    #pragma unroll 4
    for (int k = 0; k < EMB / 4; ++k) {
        float4 x = xe[k];
        #pragma unroll
        for (int q = 0; q < 4; ++q) g[q] += dot4(x, wi[q][k]);
    }
    #pragma unroll 4
    for (int k = 0; k < 256; ++k) {
        float4 x = xc[k];
        #pragma unroll
        for (int q = 0; q < 4; ++q) g[q] += dot4(x, wi[q][128 + k]);
    }
    #pragma unroll 4
    for (int k = 0; k < DDEC / 4; ++k) {
        float4 hv = h4[k];
        #pragma unroll
        for (int q = 0; q < 4; ++q) g[q] += dot4(hv, wh[q][k]);
    }
    #pragma unroll
    for (int q = 0; q < 4; ++q) g[q] += bd[q * DDEC + d];

    const float co = ccur[(long)b * DDEC + d];
    const float c2 = sigmoidf_(g[1]) * co + sigmoidf_(g[0]) * tanhf_(g[2]);
    const float h2 = sigmoidf_(g[3]) * tanhf_(c2);
    hnxt[(long)b * DDEC + d] = h2;
    cnxt[(long)b * DDEC + d] = c2;
    pred_in[((long)t * BATCH + b) * 2560 + d] = h2;
}

// ---------- small fp32 GEMM (kept for enc_part): C[M,N] = A[M,K] @ B[N,K]^T + bias ----------
__global__ __launch_bounds__(256) void gemm_abt(
    const float* __restrict__ A, int lda,
    const float* __restrict__ Bm, int ldb,
    const float* __restrict__ bias,
    float* __restrict__ C, int ldc, int K)
{
    __shared__ float As[16][68];
    __shared__ float Bs[16][68];
    const int tid = threadIdx.x;
    const int tx = tid & 15, ty = tid >> 4;
    const int lr = tid >> 2;
    const int lk = (tid & 3) << 2;
    const long m0 = (long)blockIdx.y << 6;
    const long n0 = (long)blockIdx.x << 6;
    const float* Ap = A + (m0 + lr) * lda + lk;
    const float* Bp = Bm + (n0 + lr) * ldb + lk;
    float acc[4][4] = {};

    for (int kc = 0; kc < K; kc += 16) {
        float4 av = *(const float4*)(Ap + kc);
        float4 bv = *(const float4*)(Bp + kc);
        As[lk + 0][lr] = av.x; As[lk + 1][lr] = av.y; As[lk + 2][lr] = av.z; As[lk + 3][lr] = av.w;
        Bs[lk + 0][lr] = bv.x; Bs[lk + 1][lr] = bv.y; Bs[lk + 2][lr] = bv.z; Bs[lk + 3][lr] = bv.w;
        __syncthreads();
        #pragma unroll
        for (int kk = 0; kk < 16; ++kk) {
            float4 a = *(const float4*)&As[kk][ty << 2];
            float4 b = *(const float4*)&Bs[kk][tx << 2];
            const float aa[4] = {a.x, a.y, a.z, a.w};
            const float bb2[4] = {b.x, b.y, b.z, b.w};
            #pragma unroll
            for (int i2 = 0; i2 < 4; ++i2)
                #pragma unroll
                for (int j2 = 0; j2 < 4; ++j2)
                    acc[i2][j2] += aa[i2] * bb2[j2];
        }
        __syncthreads();
    }
    float4 bvv = {0.f, 0.f, 0.f, 0.f};
    if (bias) bvv = *(const float4*)(bias + n0 + (tx << 2));
    #pragma unroll
    for (int i2 = 0; i2 < 4; ++i2) {
        float4 o;
        o.x = acc[i2][0] + bvv.x; o.y = acc[i2][1] + bvv.y;
        o.z = acc[i2][2] + bvv.z; o.w = acc[i2][3] + bvv.w;
        *(float4*)(C + (m0 + (ty << 2) + i2) * ldc + n0 + (tx << 2)) = o;
    }
}

// ---------- fp16-MFMA output projection: C[4032,32000] = A[4032,2560] @ Wo^T + bo ----------
// 128x128 tile, BK=64, 4 waves (64x64 each), reg-staged fp32->fp16 with XOR-swizzled LDS.
__global__ __launch_bounds__(256, 2) void gemm_f16_out(
    const float* __restrict__ A,    // pred_in, 4096 rows allocated (rows >=4032 garbage, guarded)
    const float* __restrict__ Bm,   // Wo [32000,2560]
    const float* __restrict__ bias, // bo [32000]
    float* __restrict__ C)          // out + 64*VOC
{
    __shared__ _Float16 As[8192];   // [128 rows][64 k] halves, swizzled
    __shared__ _Float16 Bs[8192];

    // XCD chunking + 16x10 group swizzle (grid = 32 m-tiles x 250 n-tiles = 8000)
    const int id = blockIdx.x;
    const int v = (id & 7) * 1000 + (id >> 3);
    const int g = v / 160, w = v % 160;
    const int mt = (g & 1) * 16 + (w & 15);
    const int nt = (g >> 1) * 10 + (w >> 4);

    const int t = threadIdx.x;
    const int lane = t & 63, wid = t >> 6;
    const int wr = wid >> 1, wc = wid & 1;

    // staging: thread covers rows i*16 + (t>>4), float4-col (t&15); 8 loads each for A and B
    const float4* Ag = (const float4*)A + (size_t)(mt * 128 + (t >> 4)) * 640 + (t & 15);
    const float4* Bg = (const float4*)Bm + (size_t)(nt * 128 + (t >> 4)) * 640 + (t & 15);

    int wbase = (t >> 4) * 64 + (t & 15) * 4;
    wbase ^= (((t >> 4) & 7) << 3);              // row-XOR swizzle (halves)

    // fragment read bases (XOR applied per-access to avoid carry across swizzle bits)
    const int arow = wr * 64 + (lane & 15);
    const int brow = wc * 64 + (lane & 15);
    const int abase = arow * 64 + (lane >> 4) * 8;
    const int bbase = brow * 64 + (lane >> 4) * 8;
    const int sxor = (lane & 7) << 3;

    f32x4 acc[4][4] = {};
    float4 ra[8], rb[8];
    #pragma unroll
    for (int i = 0; i < 8; ++i) { ra[i] = Ag[i * 10240]; rb[i] = Bg[i * 10240]; }

    for (int kt = 0; kt < 40; ++kt) {
        f16x4 ca[8], cb[8];
        #pragma unroll
        for (int i = 0; i < 8; ++i) {
            ca[i] = (f16x4){(_Float16)ra[i].x, (_Float16)ra[i].y, (_Float16)ra[i].z, (_Float16)ra[i].w};
            cb[i] = (f16x4){(_Float16)rb[i].x, (_Float16)rb[i].y, (_Float16)rb[i].z, (_Float16)rb[i].w};
        }
        __syncthreads();
        #pragma unroll
        for (int i = 0; i < 8; ++i) {
            *(f16x4*)&As[wbase + i * 1024] = ca[i];
            *(f16x4*)&Bs[wbase + i * 1024] = cb[i];
        }
        __syncthreads();
        if (kt < 39) {
            #pragma unroll
            for (int i = 0; i < 8; ++i) {
                ra[i] = Ag[i * 10240 + (kt + 1) * 16];
                rb[i] = Bg[i * 10240 + (kt + 1) * 16];
            }
        }
        #pragma unroll
        for (int kk = 0; kk < 2; ++kk) {
            f16x8 af[4], bfr[4];
            #pragma unroll
            for (int m = 0; m < 4; ++m) af[m]  = *(const f16x8*)&As[(abase + m * 1024 + kk * 32) ^ sxor];
            #pragma unroll
            for (int n = 0; n < 4; ++n) bfr[n] = *(const f16x8*)&Bs[(bbase + n * 1024 + kk * 32) ^ sxor];
            #pragma unroll
            for (int m = 0; m < 4; ++m)
                #pragma unroll
                for (int n = 0; n < 4; ++n)
                    acc[m][n] = __builtin_amdgcn_mfma_f32_16x16x32_f16(af[m], bfr[n], acc[m][n], 0, 0, 0);
        }
    }

    // epilogue: C/D layout col=lane&15, row=(lane>>4)*4+reg (dtype-independent)
    const int ccol0 = nt * 128 + wc * 64 + (lane & 15);
    const int crow0 = mt * 128 + wr * 64 + ((lane >> 4) << 2);
    float bv[4];
    #pragma unroll
    for (int n = 0; n < 4; ++n) bv[n] = bias[ccol0 + n * 16];
    #pragma unroll
    for (int m = 0; m < 4; ++m) {
        #pragma unroll
        for (int r = 0; r < 4; ++r) {
            const int row = crow0 + m * 16 + r;
            if (row < 4032) {
                #pragma unroll
                for (int n = 0; n < 4; ++n)
                    C[(size_t)row * VOC + ccol0 + n * 16] = acc[m][n][r] + bv[n];
            }
        }
    }
}

// ---------- launch ----------
extern "C" void kernel_launch(void* const* d_in, const int* in_sizes, int n_in,
                              void* d_out, int out_size, void* d_ws, size_t ws_size,
                              hipStream_t stream) {
    const int*   src     = (const int*)d_in[0];
    const int*   trg     = (const int*)d_in[1];
    const float* enc_emb = (const float*)d_in[2];
    const float* Wf_ih   = (const float*)d_in[3];
    const float* Wf_hh   = (const float*)d_in[4];
    const float* bf      = (const float*)d_in[5];
    const float* Wb_ih   = (const float*)d_in[6];
    const float* Wb_hh   = (const float*)d_in[7];
    const float* bb      = (const float*)d_in[8];
    const float* Wa      = (const float*)d_in[9];
    const float* ba      = (const float*)d_in[10];
    const float* vvec    = (const float*)d_in[11];
    const float* dec_emb = (const float*)d_in[12];
    const float* Wd_ih   = (const float*)d_in[13];
    const float* Wd_hh   = (const float*)d_in[14];
    const float* bd      = (const float*)d_in[15];
    const float* Wo      = (const float*)d_in[16];
    const float* bo      = (const float*)d_in[17];
    float* out = (float*)d_out;

    // workspace layout (floats)
    float* ws_f     = (float*)d_ws;
    float* enc_out  = ws_f;                       // 8388608  [S,B,2H]
    float* enc_part = enc_out + 8388608;          // 2097152  [S,B,A]
    float* hc_enc   = enc_part + 2097152;         // 262144   [2][4][B*H]
    float* h_dec    = hc_enc + 262144;            // 131072   [2][B*D]
    float* c_dec    = h_dec + 131072;             // 131072
    float* h_att    = c_dec + 131072;             // 16384    [B,A]
    float* pred_in  = h_att + 16384;              // 10485760 [4096, 2560] (4032 valid rows)
    const size_t need_bytes = (size_t)(10485760 + 16384 + 131072 + 131072 + 262144 + 2097152 + 8388608) * 4;
    if (ws_size < need_bytes) return;

    {
        long n = 131072L + 2048000L + (long)TSTEPS * BATCH * EMB;
        int blocks = (int)((n + 255) / 256);
        init_all<<<blocks, 256, 0, stream>>>(trg, dec_emb, hc_enc, out, pred_in);
    }
    for (int s = 0; s < SLEN; ++s)
        enc_step<<<256, 256, 0, stream>>>(src, enc_emb, Wf_ih, Wf_hh, bf, Wb_ih, Wb_hh, bb,
                                          hc_enc, enc_out, s);
    gemm_abt<<<dim3(ATT / 64, (SLEN * BATCH) / 64), 256, 0, stream>>>(
        enc_out, 2 * HID, Wa + 1024, 2048, ba, enc_part, ATT, 1024);
    dec_init<<<512, 256, 0, stream>>>(hc_enc, h_dec, c_dec);

    for (int t = 0; t < TSTEPS; ++t) {
        const int par = t & 1;
        const float* hcur = h_dec + par * 65536;
        const float* ccur = c_dec + par * 65536;
        float* hnxt = h_dec + (par ^ 1) * 65536;
        float* cnxt = c_dec + (par ^ 1) * 65536;
        hatt_step<<<dim3(16, 4), 256, 0, stream>>>(hcur, Wa, h_att);
        attn_step<<<BATCH, 256, 0, stream>>>(src, h_att, vvec, enc_part, enc_out, pred_in, t);
        dec_step<<<256, 256, 0, stream>>>(Wd_ih, Wd_hh, bd, hcur, ccur, hnxt, cnxt, pred_in, t);
    }
    // output projection via fp16 MFMA
    gemm_f16_out<<<8000, 256, 0, stream>>>(pred_in, Wo, bo, out + (size_t)BATCH * VOC);
}

// Round 3
// 6585.325 us; speedup vs baseline: 5.2439x; 3.8954x over previous
//
#include <hip/hip_runtime.h>

#define SLEN  128
#define BATCH 64
#define EMB   512
#define HID   512
#define DDEC  1024
#define ATT   256
#define VOC   32000
#define TSTEPS 63

typedef _Float16 f16x4 __attribute__((ext_vector_type(4)));
typedef _Float16 f16x8 __attribute__((ext_vector_type(8)));
typedef float    f32x4 __attribute__((ext_vector_type(4)));

__device__ __forceinline__ float sigmoidf_(float x) { return 1.0f / (1.0f + __expf(-x)); }
__device__ __forceinline__ float tanhf_(float x)    { return 1.0f - 2.0f / (__expf(2.0f * x) + 1.0f); }

// ================= init: zero out row0, convert weights to fp16, gather embeddings =================
__global__ __launch_bounds__(256) void init_convert(
    const int* __restrict__ src, const int* __restrict__ trg,
    const float* __restrict__ enc_emb, const float* __restrict__ dec_emb,
    const float* __restrict__ Wf_ih, const float* __restrict__ Wf_hh,
    const float* __restrict__ Wb_ih, const float* __restrict__ Wb_hh,
    const float* __restrict__ Wa, const float* __restrict__ Wd_ih, const float* __restrict__ Wd_hh,
    float* __restrict__ out0,
    _Float16* __restrict__ Wenc16, _Float16* __restrict__ Wd16, _Float16* __restrict__ Wa16,
    _Float16* __restrict__ emb_src16, _Float16* __restrict__ predA,
    float* __restrict__ c_enc, _Float16* __restrict__ h16_enc)
{
    long idx = (long)blockIdx.x * 256 + threadIdx.x;
    if (idx < 2048000L) { out0[idx] = 0.f; return; }
    idx -= 2048000L;
    if (idx < 4194304L) {   // Wenc16 [dir][2048][1024], row r=(d*4+q), cols [Wih|Whh]
        int dir = (int)(idx >> 21);
        int rem = (int)(idx & ((1 << 21) - 1));
        int rr = rem >> 10, c = rem & 1023;
        int d = rr >> 2, qg = rr & 3;
        const float* Wih = dir ? Wb_ih : Wf_ih;
        const float* Whh = dir ? Wb_hh : Wf_hh;
        float v = (c < 512) ? Wih[(long)(qg * 512 + d) * 512 + c]
                            : Whh[(long)(qg * 512 + d) * 512 + (c - 512)];
        Wenc16[idx] = (_Float16)v; return;
    }
    idx -= 4194304L;
    if (idx < 10485760L) {  // Wd16 [4096][2560], row r=(d*4+q), cols [Wd_ih(1536)|Wd_hh(1024)]
        int rr = (int)(idx / 2560), c = (int)(idx % 2560);
        int d = rr >> 2, qg = rr & 3;
        float v = (c < 1536) ? Wd_ih[(long)(qg * 1024 + d) * 1536 + c]
                             : Wd_hh[(long)(qg * 1024 + d) * 1024 + (c - 1536)];
        Wd16[idx] = (_Float16)v; return;
    }
    idx -= 10485760L;
    if (idx < 262144L) {    // Wa16 [256][1024] = Wa[:, :1024]
        int rr = (int)(idx >> 10), c = (int)(idx & 1023);
        Wa16[idx] = (_Float16)Wa[(long)rr * 2048 + c]; return;
    }
    idx -= 262144L;
    if (idx < 4194304L) {   // emb_src16 [128*64][512]
        int sb = (int)(idx >> 9), e = (int)(idx & 511);
        int tok = src[sb];
        emb_src16[idx] = (_Float16)enc_emb[(long)tok * 512 + e]; return;
    }
    idx -= 4194304L;
    if (idx < 2064384L) {   // predA emb cols: rows 64.., cols 2048..2559
        int rI = (int)(idx >> 9), e = (int)(idx & 511);
        int tok = trg[rI];
        predA[(long)(64 + rI) * 2560 + 2048 + e] = (_Float16)dec_emb[(long)tok * 512 + e]; return;
    }
    idx -= 2064384L;
    if (idx < 65536L) { c_enc[idx] = 0.f; return; }
    idx -= 65536L;
    if (idx < 65536L) { h16_enc[idx] = (_Float16)0.f; }
}

// ================= encoder step: 256 blocks x 64 thr (1 wave = 16 gates x 64 batch) =================
__global__ __launch_bounds__(64) void enc_step_mfma(
    const _Float16* __restrict__ Wenc16, const _Float16* __restrict__ emb_src16,
    _Float16* __restrict__ h16_enc, float* __restrict__ c_enc,
    const float* __restrict__ bf, const float* __restrict__ bb,
    _Float16* __restrict__ enc_out16, int s)
{
    __shared__ float gbuf[16 * 66];
    const int lane = threadIdx.x;
    const int blk = blockIdx.x;
    const int dir = blk >> 7, tile = blk & 127;
    const int par = s & 1;
    const int s_eff = dir ? (SLEN - 1 - s) : s;
    const int r16 = lane & 15, kg = lane >> 4;

    const _Float16* Bw = Wenc16 + ((size_t)(dir * 2048 + tile * 16 + r16)) * 1024 + kg * 8;
    const _Float16* Ax = emb_src16 + ((size_t)(s_eff * 64 + r16)) * 512 + kg * 8;
    const _Float16* Ah = h16_enc + ((size_t)((par * 2 + dir) * 64 + r16)) * 512 + kg * 8;

    f32x4 acc[4] = {};
    #pragma unroll 4
    for (int kc = 0; kc < 16; ++kc) {
        f16x8 bfr = *(const f16x8*)(Bw + kc * 32);
        #pragma unroll
        for (int m = 0; m < 4; ++m) {
            f16x8 a = *(const f16x8*)(Ax + kc * 32 + (size_t)m * 16 * 512);
            acc[m] = __builtin_amdgcn_mfma_f32_16x16x32_f16(a, bfr, acc[m], 0, 0, 0);
        }
    }
    #pragma unroll 4
    for (int kc = 0; kc < 16; ++kc) {
        f16x8 bfr = *(const f16x8*)(Bw + 512 + kc * 32);
        #pragma unroll
        for (int m = 0; m < 4; ++m) {
            f16x8 a = *(const f16x8*)(Ah + kc * 32 + (size_t)m * 16 * 512);
            acc[m] = __builtin_amdgcn_mfma_f32_16x16x32_f16(a, bfr, acc[m], 0, 0, 0);
        }
    }
    #pragma unroll
    for (int m = 0; m < 4; ++m)
        #pragma unroll
        for (int rI = 0; rI < 4; ++rI)
            gbuf[r16 * 66 + m * 16 + kg * 4 + rI] = acc[m][rI];
    __syncthreads();

    const float* bias = dir ? bb : bf;
    const int b = lane;
    #pragma unroll
    for (int dl = 0; dl < 4; ++dl) {
        const int d = tile * 4 + dl;
        float g0 = gbuf[(dl * 4 + 0) * 66 + b] + bias[d];
        float g1 = gbuf[(dl * 4 + 1) * 66 + b] + bias[512 + d];
        float g2 = gbuf[(dl * 4 + 2) * 66 + b] + bias[1024 + d];
        float g3 = gbuf[(dl * 4 + 3) * 66 + b] + bias[1536 + d];
        const size_t cur = ((size_t)(par * 2 + dir) * 64 + b) * 512 + d;
        const size_t nxt = ((size_t)((par ^ 1) * 2 + dir) * 64 + b) * 512 + d;
        float c2 = sigmoidf_(g1) * c_enc[cur] + sigmoidf_(g0) * tanhf_(g2);
        float h2 = sigmoidf_(g3) * tanhf_(c2);
        c_enc[nxt] = c2;
        h16_enc[nxt] = (_Float16)h2;
        enc_out16[((size_t)s_eff * 64 + b) * 1024 + dir * 512 + d] = (_Float16)h2;
    }
}

// ================= decoder init: h0 -> predA rows [0,64), c0 -> c_dec par0 =================
__global__ __launch_bounds__(256) void dec_init(
    const _Float16* __restrict__ enc_out16, const float* __restrict__ c_enc,
    _Float16* __restrict__ predA, float* __restrict__ c_dec)
{
    int idx = blockIdx.x * 256 + threadIdx.x;    // 0..131071
    int b = (idx >> 10) & 63, d = idx & 1023;
    if (idx < 65536) {
        _Float16 v = (d < 512) ? enc_out16[(size_t)(127 * 64 + b) * 1024 + d]
                               : enc_out16[(size_t)(0 * 64 + b) * 1024 + d];
        predA[(size_t)b * 2560 + d] = v;
    } else {
        float v = (d < 512) ? c_enc[((size_t)(0 * 2 + 0) * 64 + b) * 512 + d]
                            : c_enc[((size_t)(0 * 2 + 1) * 64 + b) * 512 + (d - 512)];
        c_dec[(size_t)b * 1024 + d] = v;
    }
}

// ================= hatt = h(t-1) @ Wa[:, :1024]^T via MFMA: 16 blocks x 64 thr =================
__global__ __launch_bounds__(64) void hatt_mfma(
    const _Float16* __restrict__ predA, const _Float16* __restrict__ Wa16,
    float* __restrict__ hatt, int t)
{
    const int lane = threadIdx.x;
    const int tile = blockIdx.x;
    const int r16 = lane & 15, kg = lane >> 4;
    const _Float16* Ap = predA + ((size_t)(t * 64 + r16)) * 2560 + kg * 8;
    const _Float16* Bw = Wa16 + ((size_t)(tile * 16 + r16)) * 1024 + kg * 8;
    f32x4 acc[4] = {};
    #pragma unroll 4
    for (int kc = 0; kc < 32; ++kc) {
        f16x8 bfr = *(const f16x8*)(Bw + kc * 32);
        #pragma unroll
        for (int m = 0; m < 4; ++m) {
            f16x8 a = *(const f16x8*)(Ap + kc * 32 + (size_t)m * 16 * 2560);
            acc[m] = __builtin_amdgcn_mfma_f32_16x16x32_f16(a, bfr, acc[m], 0, 0, 0);
        }
    }
    #pragma unroll
    for (int m = 0; m < 4; ++m)
        #pragma unroll
        for (int rI = 0; rI < 4; ++rI)
            hatt[(size_t)(m * 16 + kg * 4 + rI) * 256 + tile * 16 + r16] = acc[m][rI];
}

// ================= attention: energy/softmax/ctx; ctx -> predA fp16 =================
__global__ __launch_bounds__(256) void attn_step(
    const int* __restrict__ src, const float* __restrict__ hatt, const float* __restrict__ vvec,
    const _Float16* __restrict__ enc_part16, const _Float16* __restrict__ enc_out16,
    _Float16* __restrict__ predA, int t)
{
    __shared__ float ha[256], sv[256], sc[128], red[128];
    const int b = blockIdx.x, tid = threadIdx.x;
    ha[tid] = hatt[b * 256 + tid];
    sv[tid] = vvec[tid];
    __syncthreads();
    if (tid < 128) {
        const f16x8* ep = (const f16x8*)(enc_part16 + ((size_t)tid * 64 + b) * 256);
        float acc = 0.f;
        #pragma unroll 4
        for (int j8 = 0; j8 < 32; ++j8) {
            f16x8 e = ep[j8];
            #pragma unroll
            for (int u = 0; u < 8; ++u)
                acc += tanhf_(ha[j8 * 8 + u] + (float)e[u]) * sv[j8 * 8 + u];
        }
        float scv = (src[tid * 64 + b] != 0) ? acc : -1e10f;
        sc[tid] = scv; red[tid] = scv;
    }
    __syncthreads();
    for (int off = 64; off > 0; off >>= 1) { if (tid < off) red[tid] = fmaxf(red[tid], red[tid + off]); __syncthreads(); }
    const float mx = red[0];
    __syncthreads();
    if (tid < 128) { float e = __expf(sc[tid] - mx); sc[tid] = e; red[tid] = e; }
    __syncthreads();
    for (int off = 64; off > 0; off >>= 1) { if (tid < off) red[tid] += red[tid + off]; __syncthreads(); }
    const float inv = 1.0f / red[0];
    __syncthreads();

    float a0 = 0.f, a1 = 0.f, a2 = 0.f, a3 = 0.f;
    for (int sI = 0; sI < 128; ++sI) {
        float as = sc[sI] * inv;
        f16x4 ev = *(const f16x4*)(enc_out16 + ((size_t)sI * 64 + b) * 1024 + tid * 4);
        a0 += as * (float)ev[0]; a1 += as * (float)ev[1];
        a2 += as * (float)ev[2]; a3 += as * (float)ev[3];
    }
    f16x4 o = { (_Float16)a0, (_Float16)a1, (_Float16)a2, (_Float16)a3 };
    *(f16x4*)(predA + ((size_t)(64 + t * 64 + b)) * 2560 + 1024 + tid * 4) = o;
}

// ================= decoder gates+pointwise: 256 blocks x 64 thr, K=2560 =================
__global__ __launch_bounds__(64) void dec_gates(
    const _Float16* __restrict__ Wd16, const float* __restrict__ bd,
    float* __restrict__ c_dec, _Float16* __restrict__ predA, int t)
{
    __shared__ float gbuf[16 * 66];
    const int lane = threadIdx.x;
    const int tile = blockIdx.x;
    const int par = t & 1;
    const int r16 = lane & 15, kg = lane >> 4;
    const _Float16* Bw = Wd16 + ((size_t)(tile * 16 + r16)) * 2560 + kg * 8;
    const _Float16* At = predA + ((size_t)(64 + t * 64 + r16)) * 2560 + kg * 8;
    const _Float16* Ah = predA + ((size_t)(t * 64 + r16)) * 2560 + kg * 8;
    f32x4 acc[4] = {};
    #pragma unroll 4
    for (int kc = 0; kc < 16; ++kc) {   // emb: W cols 0..511, A cols 2048..2559
        f16x8 bfr = *(const f16x8*)(Bw + kc * 32);
        #pragma unroll
        for (int m = 0; m < 4; ++m) {
            f16x8 a = *(const f16x8*)(At + 2048 + kc * 32 + (size_t)m * 16 * 2560);
            acc[m] = __builtin_amdgcn_mfma_f32_16x16x32_f16(a, bfr, acc[m], 0, 0, 0);
        }
    }
    #pragma unroll 4
    for (int kc = 0; kc < 32; ++kc) {   // ctx: W cols 512..1535, A cols 1024..2047
        f16x8 bfr = *(const f16x8*)(Bw + 512 + kc * 32);
        #pragma unroll
        for (int m = 0; m < 4; ++m) {
            f16x8 a = *(const f16x8*)(At + 1024 + kc * 32 + (size_t)m * 16 * 2560);
            acc[m] = __builtin_amdgcn_mfma_f32_16x16x32_f16(a, bfr, acc[m], 0, 0, 0);
        }
    }
    #pragma unroll 4
    for (int kc = 0; kc < 32; ++kc) {   // h: W cols 1536..2559, A(row t-1) cols 0..1023
        f16x8 bfr = *(const f16x8*)(Bw + 1536 + kc * 32);
        #pragma unroll
        for (int m = 0; m < 4; ++m) {
            f16x8 a = *(const f16x8*)(Ah + kc * 32 + (size_t)m * 16 * 2560);
            acc[m] = __builtin_amdgcn_mfma_f32_16x16x32_f16(a, bfr, acc[m], 0, 0, 0);
        }
    }
    #pragma unroll
    for (int m = 0; m < 4; ++m)
        #pragma unroll
        for (int rI = 0; rI < 4; ++rI)
            gbuf[r16 * 66 + m * 16 + kg * 4 + rI] = acc[m][rI];
    __syncthreads();

    const int b = lane;
    #pragma unroll
    for (int dl = 0; dl < 4; ++dl) {
        const int d = tile * 4 + dl;
        float g0 = gbuf[(dl * 4 + 0) * 66 + b] + bd[d];
        float g1 = gbuf[(dl * 4 + 1) * 66 + b] + bd[1024 + d];
        float g2 = gbuf[(dl * 4 + 2) * 66 + b] + bd[2048 + d];
        float g3 = gbuf[(dl * 4 + 3) * 66 + b] + bd[3072 + d];
        float c2 = sigmoidf_(g1) * c_dec[(size_t)(par * 64 + b) * 1024 + d] + sigmoidf_(g0) * tanhf_(g2);
        float h2 = sigmoidf_(g3) * tanhf_(c2);
        c_dec[(size_t)((par ^ 1) * 64 + b) * 1024 + d] = c2;
        predA[((size_t)(64 + t * 64 + b)) * 2560 + d] = (_Float16)h2;
    }
}

// ================= generic fp16-A MFMA GEMM: C[M,N] = A16[M,K] @ B32[N,K]^T + bias =================
// 128x128 tile, BK=64, 4 waves. B converted fp32->fp16 in-flight. XOR-swizzled LDS.
__global__ __launch_bounds__(256, 2) void gemm_a16(
    const _Float16* __restrict__ A, int lda,
    const float* __restrict__ B, int ldb,
    const float* __restrict__ bias,
    void* __restrict__ Cv, int ldc, int K, int Mvalid, int ntn, int c16)
{
    __shared__ _Float16 As[8192];
    __shared__ _Float16 Bs[8192];

    const int nwg = gridDim.x;
    const int id = blockIdx.x;
    const int q = nwg >> 3, r = nwg & 7;
    const int xcd = id & 7, ix = id >> 3;
    const int wg = (xcd < r) ? (xcd * (q + 1) + ix) : (r * (q + 1) + (xcd - r) * q + ix);
    const int per = ntn << 3;
    const int g = wg / per, rem = wg % per;
    const int mt = g * 8 + (rem & 7), nt = rem >> 3;

    const int t = threadIdx.x, lane = t & 63, wid = t >> 6;
    const int wr = wid >> 1, wc = wid & 1;

    const int arow_s = t >> 3, ac8 = t & 7;       // A stage: 4 frags, rows +32
    const int brow_s = t >> 4, bc4 = t & 15;      // B stage: 8 frags, rows +16
    const _Float16* Ap = A + (size_t)(mt * 128 + arow_s) * lda + ac8 * 8;
    const float*    Bp = B + (size_t)(nt * 128 + brow_s) * ldb + bc4 * 4;
    const int awx = (ac8 * 8) ^ ((arow_s & 7) << 3);
    const int bwx = (bc4 * 4) ^ ((brow_s & 7) << 3);

    const int kts = K >> 6;
    f32x4 acc[4][4] = {};
    f16x8 ra[4]; float4 rb[8];
    #pragma unroll
    for (int i = 0; i < 4; ++i) ra[i] = *(const f16x8*)(Ap + (size_t)i * 32 * lda);
    #pragma unroll
    for (int i = 0; i < 8; ++i) rb[i] = *(const float4*)(Bp + (size_t)i * 16 * ldb);

    const int abase = (wr * 64 + (lane & 15)) * 64 + (lane >> 4) * 8;
    const int bbase = (wc * 64 + (lane & 15)) * 64 + (lane >> 4) * 8;
    const int sxor = (lane & 7) << 3;

    for (int kt = 0; kt < kts; ++kt) {
        f16x4 cb[8];
        #pragma unroll
        for (int i = 0; i < 8; ++i)
            cb[i] = (f16x4){(_Float16)rb[i].x, (_Float16)rb[i].y, (_Float16)rb[i].z, (_Float16)rb[i].w};
        __syncthreads();
        #pragma unroll
        for (int i = 0; i < 4; ++i)
            *(f16x8*)&As[(arow_s + i * 32) * 64 + awx] = ra[i];
        #pragma unroll
        for (int i = 0; i < 8; ++i)
            *(f16x4*)&Bs[(brow_s + i * 16) * 64 + bwx] = cb[i];
        __syncthreads();
        if (kt + 1 < kts) {
            #pragma unroll
            for (int i = 0; i < 4; ++i) ra[i] = *(const f16x8*)(Ap + (size_t)i * 32 * lda + (kt + 1) * 64);
            #pragma unroll
            for (int i = 0; i < 8; ++i) rb[i] = *(const float4*)(Bp + (size_t)i * 16 * ldb + (kt + 1) * 64);
        }
        #pragma unroll
        for (int kk = 0; kk < 2; ++kk) {
            f16x8 af[4], bfr[4];
            #pragma unroll
            for (int m = 0; m < 4; ++m) af[m]  = *(const f16x8*)&As[(abase + m * 16 * 64 + kk * 32) ^ sxor];
            #pragma unroll
            for (int n = 0; n < 4; ++n) bfr[n] = *(const f16x8*)&Bs[(bbase + n * 16 * 64 + kk * 32) ^ sxor];
            #pragma unroll
            for (int m = 0; m < 4; ++m)
                #pragma unroll
                for (int n = 0; n < 4; ++n)
                    acc[m][n] = __builtin_amdgcn_mfma_f32_16x16x32_f16(af[m], bfr[n], acc[m][n], 0, 0, 0);
        }
    }

    const int ccol = nt * 128 + wc * 64 + (lane & 15);
    const int crow0 = mt * 128 + wr * 64 + ((lane >> 4) << 2);
    float bv[4];
    #pragma unroll
    for (int n = 0; n < 4; ++n) bv[n] = bias[ccol + n * 16];
    #pragma unroll
    for (int m = 0; m < 4; ++m) {
        #pragma unroll
        for (int rI = 0; rI < 4; ++rI) {
            const int row = crow0 + m * 16 + rI;
            if (row < Mvalid) {
                if (c16) {
                    _Float16* C = (_Float16*)Cv;
                    #pragma unroll
                    for (int n = 0; n < 4; ++n)
                        C[(size_t)row * ldc + ccol + n * 16] = (_Float16)(acc[m][n][rI] + bv[n]);
                } else {
                    float* C = (float*)Cv;
                    #pragma unroll
                    for (int n = 0; n < 4; ++n)
                        C[(size_t)row * ldc + ccol + n * 16] = acc[m][n][rI] + bv[n];
                }
            }
        }
    }
}

// ================= launch =================
extern "C" void kernel_launch(void* const* d_in, const int* in_sizes, int n_in,
                              void* d_out, int out_size, void* d_ws, size_t ws_size,
                              hipStream_t stream) {
    const int*   src     = (const int*)d_in[0];
    const int*   trg     = (const int*)d_in[1];
    const float* enc_emb = (const float*)d_in[2];
    const float* Wf_ih   = (const float*)d_in[3];
    const float* Wf_hh   = (const float*)d_in[4];
    const float* bf      = (const float*)d_in[5];
    const float* Wb_ih   = (const float*)d_in[6];
    const float* Wb_hh   = (const float*)d_in[7];
    const float* bb      = (const float*)d_in[8];
    const float* Wa      = (const float*)d_in[9];
    const float* ba      = (const float*)d_in[10];
    const float* vvec    = (const float*)d_in[11];
    const float* dec_emb = (const float*)d_in[12];
    const float* Wd_ih   = (const float*)d_in[13];
    const float* Wd_hh   = (const float*)d_in[14];
    const float* bd      = (const float*)d_in[15];
    const float* Wo      = (const float*)d_in[16];
    const float* bo      = (const float*)d_in[17];
    float* out = (float*)d_out;

    // workspace layout (byte offsets)
    char* w = (char*)d_ws;
    _Float16* Wenc16     = (_Float16*)(w);               // 8,388,608 B
    _Float16* Wd16       = (_Float16*)(w + 8388608);     // 20,971,520 B
    _Float16* Wa16       = (_Float16*)(w + 29360128);    // 524,288 B
    _Float16* emb_src16  = (_Float16*)(w + 29884416);    // 8,388,608 B
    _Float16* enc_out16  = (_Float16*)(w + 38273024);    // 16,777,216 B
    _Float16* predA      = (_Float16*)(w + 55050240);    // 21,299,200 B (4160 x 2560)
    _Float16* h16_enc    = (_Float16*)(w + 76349440);    // 262,144 B
    float*    c_enc      = (float*)   (w + 76611584);    // 524,288 B
    float*    c_dec      = (float*)   (w + 77135872);    // 524,288 B
    float*    hatt       = (float*)   (w + 77660160);    // 65,536 B
    _Float16* enc_part16 = (_Float16*)(w + 77725696);    // 4,194,304 B
    const size_t need_bytes = 81920000;
    if (ws_size < need_bytes) return;

    init_convert<<<91328, 256, 0, stream>>>(
        src, trg, enc_emb, dec_emb, Wf_ih, Wf_hh, Wb_ih, Wb_hh, Wa, Wd_ih, Wd_hh,
        out, Wenc16, Wd16, Wa16, emb_src16, predA, c_enc, h16_enc);

    for (int s = 0; s < SLEN; ++s)
        enc_step_mfma<<<256, 64, 0, stream>>>(Wenc16, emb_src16, h16_enc, c_enc, bf, bb, enc_out16, s);

    // enc_part16 = enc_out16 @ Wa[:,1024:]^T + ba   (M=8192, N=256, K=1024, fp16 out)
    gemm_a16<<<128, 256, 0, stream>>>(enc_out16, 1024, Wa + 1024, 2048, ba,
                                      enc_part16, 256, 1024, 8192, 2, 1);

    dec_init<<<512, 256, 0, stream>>>(enc_out16, c_enc, predA, c_dec);

    for (int t = 0; t < TSTEPS; ++t) {
        hatt_mfma<<<16, 64, 0, stream>>>(predA, Wa16, hatt, t);
        attn_step<<<64, 256, 0, stream>>>(src, hatt, vvec, enc_part16, enc_out16, predA, t);
        dec_gates<<<256, 64, 0, stream>>>(Wd16, bd, c_dec, predA, t);
    }

    // out[64.. , :] = predA[64..] @ Wo^T + bo   (M=4032 valid, N=32000, K=2560)
    gemm_a16<<<8000, 256, 0, stream>>>(predA + (size_t)64 * 2560, 2560, Wo, 2560, bo,
                                       out + (size_t)64 * VOC, VOC, 2560, 4032, 250, 0);
}